// Round 1
// baseline (1689.078 us; speedup 1.0000x reference)
//
#include <hip/hip_runtime.h>

#define NN 100000
#define NE 1600000
#define D 64

// xw[r][j] = sum_k x[r][k] * W[k][j]   (W row-major 64x64, staged in LDS)
__global__ void gemm64(const float* __restrict__ x, const float* __restrict__ W,
                       float* __restrict__ out, int n) {
    __shared__ float sW[D * D];
    int tid = threadIdx.x;
    for (int i = tid; i < D * D; i += blockDim.x) sW[i] = W[i];
    __syncthreads();
    int lane = tid & 63;
    int gwave = (int)((blockIdx.x * blockDim.x + tid) >> 6);
    int nw = (int)((gridDim.x * blockDim.x) >> 6);
    for (int r = gwave; r < n; r += nw) {
        float xv = x[(size_t)r * D + lane];
        float acc = 0.f;
#pragma unroll
        for (int k = 0; k < D; ++k) {
            float xk = __shfl(xv, k, 64);
            acc = fmaf(xk, sW[k * D + lane], acc);
        }
        out[(size_t)r * D + lane] = acc;
    }
}

// h[i][j] = ori[i][j] + b[j]   (RESIDUAL = 1.0 folded in; bias folded in)
__global__ void init_out(const float* __restrict__ ori, const float* __restrict__ b,
                         float* __restrict__ h, int total) {
    int idx = blockIdx.x * blockDim.x + threadIdx.x;
    int stride = gridDim.x * blockDim.x;
    for (int i = idx; i < total; i += stride) {
        h[i] = ori[i] + b[i & (D - 1)];
    }
}

// for each edge e: h[dst[e]][lane] += xw[src[e]][lane] * w[e]
__global__ void edge_scatter(const float* __restrict__ xw, const float* __restrict__ w,
                             const int* __restrict__ src, const int* __restrict__ dst,
                             float* __restrict__ h, int ne) {
    int lane = threadIdx.x & 63;
    int gwave = (int)((blockIdx.x * blockDim.x + threadIdx.x) >> 6);
    int nw = (int)((gridDim.x * blockDim.x) >> 6);
    for (int e = gwave; e < ne; e += nw) {
        int s = src[e];
        int d = dst[e];
        float we = w[e];
        float v = xw[(size_t)s * D + lane] * we;
        atomicAdd(&h[(size_t)d * D + lane], v);
    }
}

extern "C" void kernel_launch(void* const* d_in, const int* in_sizes, int n_in,
                              void* d_out, int out_size, void* d_ws, size_t ws_size,
                              hipStream_t stream) {
    const float* in_feat = (const float*)d_in[0];
    const float* ew      = (const float*)d_in[1];
    const float* W1      = (const float*)d_in[2];
    const float* b1      = (const float*)d_in[3];
    const float* W2      = (const float*)d_in[4];
    const float* b2      = (const float*)d_in[5];
    const int*   src     = (const int*)d_in[6];
    const int*   dst     = (const int*)d_in[7];
    float* out = (float*)d_out;

    float* xw = (float*)d_ws;
    float* h  = xw + (size_t)NN * D;

    const int total = NN * D;

    // step 1: h1 = A(in_feat @ W1) + b1 + ori
    gemm64<<<2048, 256, 0, stream>>>(in_feat, W1, xw, NN);
    init_out<<<2048, 256, 0, stream>>>(in_feat, b1, h, total);
    edge_scatter<<<4096, 256, 0, stream>>>(xw, ew, src, dst, h, NE);

    // steps 2,3: h = A(h @ W2) + b2 + ori
    for (int s = 0; s < 2; ++s) {
        gemm64<<<2048, 256, 0, stream>>>(h, W2, xw, NN);
        init_out<<<2048, 256, 0, stream>>>(in_feat, b2, h, total);
        edge_scatter<<<4096, 256, 0, stream>>>(xw, ew, src, dst, h, NE);
    }

    // step 4 -> out
    gemm64<<<2048, 256, 0, stream>>>(h, W2, xw, NN);
    init_out<<<2048, 256, 0, stream>>>(in_feat, b2, out, total);
    edge_scatter<<<4096, 256, 0, stream>>>(xw, ew, src, dst, out, NE);
}

// Round 2
// 893.390 us; speedup vs baseline: 1.8906x; 1.8906x over previous
//
#include <hip/hip_runtime.h>

#define NN 100000
#define NE 1600000
#define D 64
#define SCAN_T 512
#define NTILES ((NN + SCAN_T - 1) / SCAN_T)   // 196

// ---------- dense GEMM: xw[r][j] = sum_k x[r][k] * W[k][j] ----------
__global__ void gemm64(const float* __restrict__ x, const float* __restrict__ W,
                       float* __restrict__ out, int n) {
    __shared__ float sW[D * D];
    int tid = threadIdx.x;
    for (int i = tid; i < D * D; i += blockDim.x) sW[i] = W[i];
    __syncthreads();
    int lane = tid & 63;
    int gwave = (int)((blockIdx.x * blockDim.x + tid) >> 6);
    int nw = (int)((gridDim.x * blockDim.x) >> 6);
    for (int r = gwave; r < n; r += nw) {
        float xv = x[(size_t)r * D + lane];
        float acc = 0.f;
#pragma unroll
        for (int k = 0; k < D; ++k) {
            float xk = __shfl(xv, k, 64);
            acc = fmaf(xk, sW[k * D + lane], acc);
        }
        out[(size_t)r * D + lane] = acc;
    }
}

// ---------- CSR build ----------
__global__ void hist_dst(const int* __restrict__ dst, int* __restrict__ counts, int ne) {
    int idx = blockIdx.x * blockDim.x + threadIdx.x;
    int stride = gridDim.x * blockDim.x;
    for (int e = idx; e < ne; e += stride) atomicAdd(&counts[dst[e]], 1);
}

// per-tile exclusive scan; tile sums out
__global__ void scan_tile(const int* __restrict__ counts, int* __restrict__ excl,
                          int* __restrict__ tilesum, int n) {
    __shared__ int s[SCAN_T];
    int t = threadIdx.x;
    int g = blockIdx.x * SCAN_T + t;
    int v = (g < n) ? counts[g] : 0;
    s[t] = v;
    __syncthreads();
    for (int off = 1; off < SCAN_T; off <<= 1) {
        int x = (t >= off) ? s[t - off] : 0;
        __syncthreads();
        s[t] += x;
        __syncthreads();
    }
    if (g < n) excl[g] = s[t] - v;
    if (t == SCAN_T - 1) tilesum[blockIdx.x] = s[t];
}

// single-block exclusive scan of tile sums (NTILES <= 256)
__global__ void scan_sums(int* __restrict__ tilesum, int ntiles) {
    __shared__ int s[256];
    int t = threadIdx.x;
    int v = (t < ntiles) ? tilesum[t] : 0;
    s[t] = v;
    __syncthreads();
    for (int off = 1; off < 256; off <<= 1) {
        int x = (t >= off) ? s[t - off] : 0;
        __syncthreads();
        s[t] += x;
        __syncthreads();
    }
    if (t < ntiles) tilesum[t] = s[t] - v;
}

__global__ void scan_add(const int* __restrict__ excl, const int* __restrict__ tilesum,
                         int* __restrict__ offsets, int* __restrict__ pos, int n, int ne) {
    int g = blockIdx.x * SCAN_T + threadIdx.x;
    if (g < n) {
        int o = excl[g] + tilesum[blockIdx.x];
        offsets[g] = o;
        pos[g] = o;
    }
    if (g == 0) offsets[n] = ne;
}

__global__ void reorder(const int* __restrict__ src, const int* __restrict__ dst,
                        const float* __restrict__ w, int* __restrict__ pos,
                        int* __restrict__ ssrc, float* __restrict__ sw, int ne) {
    int idx = blockIdx.x * blockDim.x + threadIdx.x;
    int stride = gridDim.x * blockDim.x;
    for (int e = idx; e < ne; e += stride) {
        int p = atomicAdd(&pos[dst[e]], 1);
        ssrc[p] = src[e];
        sw[p] = w[e];
    }
}

// ---------- pull aggregation: out[v] = sum_in xw[src]*w + b + ori[v] ----------
__global__ void pull_agg(const float* __restrict__ xw, const int* __restrict__ ssrc,
                         const float* __restrict__ sw, const int* __restrict__ offsets,
                         const float* __restrict__ ori, const float* __restrict__ b,
                         float* __restrict__ out, int n) {
    int lane = threadIdx.x & 63;
    int gwave = (int)((blockIdx.x * blockDim.x + threadIdx.x) >> 6);
    int nw = (int)((gridDim.x * blockDim.x) >> 6);
    float bias = b[lane];
    for (int v = gwave; v < n; v += nw) {
        int e0 = offsets[v];
        int e1 = offsets[v + 1];
        float acc = ori[(size_t)v * D + lane] + bias;
        for (int base = e0; base < e1; base += 64) {
            int m = e1 - base;
            if (m > 64) m = 64;
            int my_s = 0;
            float my_w = 0.f;
            if (lane < m) {
                my_s = ssrc[base + lane];
                my_w = sw[base + lane];
            }
            for (int j = 0; j < m; ++j) {
                int s = __shfl(my_s, j, 64);
                float wj = __shfl(my_w, j, 64);
                acc = fmaf(xw[(size_t)s * D + lane], wj, acc);
            }
        }
        out[(size_t)v * D + lane] = acc;
    }
}

extern "C" void kernel_launch(void* const* d_in, const int* in_sizes, int n_in,
                              void* d_out, int out_size, void* d_ws, size_t ws_size,
                              hipStream_t stream) {
    const float* in_feat = (const float*)d_in[0];
    const float* ew      = (const float*)d_in[1];
    const float* W1      = (const float*)d_in[2];
    const float* b1      = (const float*)d_in[3];
    const float* W2      = (const float*)d_in[4];
    const float* b2      = (const float*)d_in[5];
    const int*   src     = (const int*)d_in[6];
    const int*   dst     = (const int*)d_in[7];
    float* out = (float*)d_out;

    // workspace layout (all 4-byte elems): ~66 MB
    float* xw      = (float*)d_ws;                 // NN*D
    float* h       = xw + (size_t)NN * D;          // NN*D
    int*   counts  = (int*)(h + (size_t)NN * D);   // NN
    int*   excl    = counts + NN;                  // NN
    int*   offsets = excl + NN;                    // NN+1
    int*   pos     = offsets + NN + 1;             // NN
    int*   tilesum = pos + NN;                     // 256
    int*   ssrc    = tilesum + 256;                // NE
    float* sw      = (float*)(ssrc + NE);          // NE

    // ---- build CSR by dst (once; reused for all 4 steps) ----
    hipMemsetAsync(counts, 0, NN * sizeof(int), stream);
    hist_dst<<<2048, 256, 0, stream>>>(dst, counts, NE);
    scan_tile<<<NTILES, SCAN_T, 0, stream>>>(counts, excl, tilesum, NN);
    scan_sums<<<1, 256, 0, stream>>>(tilesum, NTILES);
    scan_add<<<NTILES, SCAN_T, 0, stream>>>(excl, tilesum, offsets, pos, NN, NE);
    reorder<<<4096, 256, 0, stream>>>(src, dst, ew, pos, ssrc, sw, NE);

    // ---- 4 propagation steps ----
    // step 1: h = A(in_feat @ W1) + b1 + ori
    gemm64<<<2048, 256, 0, stream>>>(in_feat, W1, xw, NN);
    pull_agg<<<2048, 256, 0, stream>>>(xw, ssrc, sw, offsets, in_feat, b1, h, NN);

    // steps 2,3: h = A(h @ W2) + b2 + ori
    for (int s = 0; s < 2; ++s) {
        gemm64<<<2048, 256, 0, stream>>>(h, W2, xw, NN);
        pull_agg<<<2048, 256, 0, stream>>>(xw, ssrc, sw, offsets, in_feat, b2, h, NN);
    }

    // step 4 -> out
    gemm64<<<2048, 256, 0, stream>>>(h, W2, xw, NN);
    pull_agg<<<2048, 256, 0, stream>>>(xw, ssrc, sw, offsets, in_feat, b2, out, NN);
}

// Round 3
// 699.084 us; speedup vs baseline: 2.4161x; 1.2779x over previous
//
#include <hip/hip_runtime.h>
#include <hip/hip_fp16.h>

#define NN 100000
#define NE 1600000
#define D 64
#define SCAN_T 512
#define NTILES ((NN + SCAN_T - 1) / SCAN_T)   // 196

// ---------- dense GEMM: xw[r][j] = (sum_k x[r][k] * W[k][j]) -> fp16 ----------
__global__ void gemm64h(const float* __restrict__ x, const float* __restrict__ W,
                        __half* __restrict__ out, int n) {
    __shared__ float sW[D * D];
    int tid = threadIdx.x;
    for (int i = tid; i < D * D; i += blockDim.x) sW[i] = W[i];
    __syncthreads();
    int lane = tid & 63;
    int gwave = (int)((blockIdx.x * blockDim.x + tid) >> 6);
    int nw = (int)((gridDim.x * blockDim.x) >> 6);
    for (int r = gwave; r < n; r += nw) {
        float xv = x[(size_t)r * D + lane];
        float acc = 0.f;
#pragma unroll
        for (int k = 0; k < D; ++k) {
            float xk = __shfl(xv, k, 64);
            acc = fmaf(xk, sW[k * D + lane], acc);
        }
        out[(size_t)r * D + lane] = __float2half(acc);
    }
}

// ---------- CSR build ----------
__global__ void hist_dst(const int* __restrict__ dst, int* __restrict__ counts, int ne) {
    int idx = blockIdx.x * blockDim.x + threadIdx.x;
    int stride = gridDim.x * blockDim.x;
    for (int e = idx; e < ne; e += stride) atomicAdd(&counts[dst[e]], 1);
}

__global__ void scan_tile(const int* __restrict__ counts, int* __restrict__ excl,
                          int* __restrict__ tilesum, int n) {
    __shared__ int s[SCAN_T];
    int t = threadIdx.x;
    int g = blockIdx.x * SCAN_T + t;
    int v = (g < n) ? counts[g] : 0;
    s[t] = v;
    __syncthreads();
    for (int off = 1; off < SCAN_T; off <<= 1) {
        int x = (t >= off) ? s[t - off] : 0;
        __syncthreads();
        s[t] += x;
        __syncthreads();
    }
    if (g < n) excl[g] = s[t] - v;
    if (t == SCAN_T - 1) tilesum[blockIdx.x] = s[t];
}

__global__ void scan_sums(int* __restrict__ tilesum, int ntiles) {
    __shared__ int s[256];
    int t = threadIdx.x;
    int v = (t < ntiles) ? tilesum[t] : 0;
    s[t] = v;
    __syncthreads();
    for (int off = 1; off < 256; off <<= 1) {
        int x = (t >= off) ? s[t - off] : 0;
        __syncthreads();
        s[t] += x;
        __syncthreads();
    }
    if (t < ntiles) tilesum[t] = s[t] - v;
}

__global__ void scan_add(const int* __restrict__ excl, const int* __restrict__ tilesum,
                         int* __restrict__ offsets, int* __restrict__ pos, int n, int ne) {
    int g = blockIdx.x * SCAN_T + threadIdx.x;
    if (g < n) {
        int o = excl[g] + tilesum[blockIdx.x];
        offsets[g] = o;
        pos[g] = o;
    }
    if (g == 0) offsets[n] = ne;
}

// packed (src, weight-bits) per edge -> one 8B store per edge
__global__ void reorder(const int* __restrict__ src, const int* __restrict__ dst,
                        const float* __restrict__ w, int* __restrict__ pos,
                        int2* __restrict__ sew, int ne) {
    int idx = blockIdx.x * blockDim.x + threadIdx.x;
    int stride = gridDim.x * blockDim.x;
    for (int e = idx; e < ne; e += stride) {
        int p = atomicAdd(&pos[dst[e]], 1);
        sew[p] = make_int2(src[e], __float_as_int(w[e]));
    }
}

// ---------- pull aggregation: out[v] = sum_in xw[src]*w + b + ori[v] ----------
__global__ void pull_agg(const __half* __restrict__ xw, const int2* __restrict__ sew,
                         const int* __restrict__ offsets,
                         const float* __restrict__ ori, const float* __restrict__ b,
                         float* __restrict__ out, int n) {
    int lane = threadIdx.x & 63;
    int gwave = (int)((blockIdx.x * blockDim.x + threadIdx.x) >> 6);
    int nw = (int)((gridDim.x * blockDim.x) >> 6);
    float bias = b[lane];
    for (int v = gwave; v < n; v += nw) {
        int e0 = offsets[v];
        int e1 = offsets[v + 1];
        float acc = ori[(size_t)v * D + lane] + bias;
        for (int base = e0; base < e1; base += 64) {
            int m = e1 - base;
            if (m > 64) m = 64;
            int my_s = 0;
            float my_w = 0.f;
            if (lane < m) {
                int2 p = sew[base + lane];
                my_s = p.x;
                my_w = __int_as_float(p.y);
            }
            int j = 0;
            for (; j + 4 <= m; j += 4) {
                int s0 = __shfl(my_s, j, 64);
                int s1 = __shfl(my_s, j + 1, 64);
                int s2 = __shfl(my_s, j + 2, 64);
                int s3 = __shfl(my_s, j + 3, 64);
                float w0 = __shfl(my_w, j, 64);
                float w1 = __shfl(my_w, j + 1, 64);
                float w2 = __shfl(my_w, j + 2, 64);
                float w3 = __shfl(my_w, j + 3, 64);
                float v0 = __half2float(xw[(size_t)s0 * D + lane]);
                float v1 = __half2float(xw[(size_t)s1 * D + lane]);
                float v2 = __half2float(xw[(size_t)s2 * D + lane]);
                float v3 = __half2float(xw[(size_t)s3 * D + lane]);
                acc = fmaf(v0, w0, acc);
                acc = fmaf(v1, w1, acc);
                acc = fmaf(v2, w2, acc);
                acc = fmaf(v3, w3, acc);
            }
            for (; j < m; ++j) {
                int s = __shfl(my_s, j, 64);
                float wj = __shfl(my_w, j, 64);
                acc = fmaf(__half2float(xw[(size_t)s * D + lane]), wj, acc);
            }
        }
        out[(size_t)v * D + lane] = acc;
    }
}

extern "C" void kernel_launch(void* const* d_in, const int* in_sizes, int n_in,
                              void* d_out, int out_size, void* d_ws, size_t ws_size,
                              hipStream_t stream) {
    const float* in_feat = (const float*)d_in[0];
    const float* ew      = (const float*)d_in[1];
    const float* W1      = (const float*)d_in[2];
    const float* b1      = (const float*)d_in[3];
    const float* W2      = (const float*)d_in[4];
    const float* b2      = (const float*)d_in[5];
    const int*   src     = (const int*)d_in[6];
    const int*   dst     = (const int*)d_in[7];
    float* out = (float*)d_out;

    // workspace layout (~53 MB)
    char* base = (char*)d_ws;
    int2*   sew     = (int2*)base;                               // NE * 8B
    float*  h       = (float*)(base + (size_t)NE * 8);           // NN*D * 4B
    __half* xw      = (__half*)(h + (size_t)NN * D);             // NN*D * 2B
    int*    counts  = (int*)(xw + (size_t)NN * D);               // NN
    int*    excl    = counts + NN;                               // NN
    int*    offsets = excl + NN;                                 // NN+1
    int*    pos     = offsets + NN + 1;                          // NN
    int*    tilesum = pos + NN;                                  // 256

    // ---- build CSR by dst (once; reused for all 4 steps) ----
    hipMemsetAsync(counts, 0, NN * sizeof(int), stream);
    hist_dst<<<2048, 256, 0, stream>>>(dst, counts, NE);
    scan_tile<<<NTILES, SCAN_T, 0, stream>>>(counts, excl, tilesum, NN);
    scan_sums<<<1, 256, 0, stream>>>(tilesum, NTILES);
    scan_add<<<NTILES, SCAN_T, 0, stream>>>(excl, tilesum, offsets, pos, NN, NE);
    reorder<<<4096, 256, 0, stream>>>(src, dst, ew, pos, sew, NE);

    // ---- 4 propagation steps ----
    gemm64h<<<2048, 256, 0, stream>>>(in_feat, W1, xw, NN);
    pull_agg<<<2048, 256, 0, stream>>>(xw, sew, offsets, in_feat, b1, h, NN);

    for (int s = 0; s < 2; ++s) {
        gemm64h<<<2048, 256, 0, stream>>>(h, W2, xw, NN);
        pull_agg<<<2048, 256, 0, stream>>>(xw, sew, offsets, in_feat, b2, h, NN);
    }

    gemm64h<<<2048, 256, 0, stream>>>(h, W2, xw, NN);
    pull_agg<<<2048, 256, 0, stream>>>(xw, sew, offsets, in_feat, b2, out, NN);
}